// Round 1
// baseline (1608.107 us; speedup 1.0000x reference)
//
#include <hip/hip_runtime.h>
#include <hip/hip_bf16.h>

#define BATCH 2048
#define DIM   2048
#define KR    49     // K_REG (= L, number of V slots)
#define KC    64     // K-chunk of D per MFMA step
#define NROW  (BATCH * KR)   // 100352 flattened V rows (divisible by 64)

typedef __attribute__((ext_vector_type(8))) short short8;   // 8 bf16 = 4 VGPRs
typedef __attribute__((ext_vector_type(4))) float float4v;  // MFMA accumulator

__device__ __forceinline__ unsigned short f2b(float x) {
    __hip_bfloat16 h = __float2bfloat16(x);
    return __builtin_bit_cast(unsigned short, h);
}

// pack two fp32 -> two bf16 (truncate toward zero: keep high 16 bits)
__device__ __forceinline__ unsigned int pack2_trunc(float lo, float hi) {
    unsigned int a = __builtin_bit_cast(unsigned int, lo);
    unsigned int b = __builtin_bit_cast(unsigned int, hi);
    return (b & 0xffff0000u) | (a >> 16);
}

// Kernel 1: W_gt[b,k] = h_t[b]·W_g[k];  Ts[b,k] = tanh(s_t[b]·W_s[k] + W_gt)·w_h_s[k];
// plus fp32->bf16 (RNE) conversion of W_v.
__global__ __launch_bounds__(256) void precompute_kernel(
    const float* __restrict__ h_t, const float* __restrict__ s_t,
    const float* __restrict__ W_v, const float* __restrict__ W_g,
    const float* __restrict__ W_s, const float* __restrict__ w_h_s,
    float* __restrict__ Wgt, float* __restrict__ Ts,
    unsigned short* __restrict__ Wvb)
{
    const int idx = blockIdx.x * 256 + threadIdx.x;
    if (idx >= BATCH * KR) return;
    Wvb[idx] = f2b(W_v[idx]);          // exact 1:1 cover of 49*2048 elements
    const int b = idx / KR;
    const int k = idx - b * KR;
    const float4* h4 = (const float4*)(h_t + (size_t)b * DIM);
    const float4* s4 = (const float4*)(s_t + (size_t)b * DIM);
    const float4* g4 = (const float4*)(W_g + (size_t)k * DIM);
    const float4* w4 = (const float4*)(W_s + (size_t)k * DIM);
    float ag = 0.f, as = 0.f;
    #pragma unroll 4
    for (int d = 0; d < DIM / 4; ++d) {
        float4 hv = h4[d], gv = g4[d];
        ag += hv.x * gv.x + hv.y * gv.y + hv.z * gv.z + hv.w * gv.w;
        float4 sv = s4[d], wv = w4[d];
        as += sv.x * wv.x + sv.y * wv.y + sv.z * wv.z + sv.w * wv.w;
    }
    Wgt[idx] = ag;
    Ts[idx]  = tanhf(as + ag) * w_h_s[k];
}

// Kernel 2: flat z-GEMM over the flattened (B*KR, DIM) V matrix.
// Each block handles 64 REAL consecutive rows (no duplicate-row padding waste).
// Per wave: 16 rows x 64 cols (49 used), K=DIM via bf16 MFMA, fragments direct
// from global (no LDS, no barriers). Epilogue fuses z_row = sum_k tanh(T+Wgt)*w_h.
__global__ __launch_bounds__(256) void z_gemm_kernel(
    const float* __restrict__ V, const unsigned short* __restrict__ Wvb,
    const float* __restrict__ Wgt, const float* __restrict__ w_h,
    float* __restrict__ zbuf)
{
    const int tid  = threadIdx.x;
    const int wave = tid >> 6;
    const int lane = tid & 63;
    const int quad = lane >> 4;
    const int l16  = lane & 15;

    const int rbase = blockIdx.x * 64 + wave * 16;   // global flattened row base

    // A row for this lane (MFMA A layout: m = l16). All 16 rows are real.
    const float* aBase = V + (size_t)(rbase + l16) * DIM + quad * 8;

    // B rows for the 4 col-tiles (n = t*16 + l16), clamped into [0,KR).
    const unsigned short* bBase[4];
    #pragma unroll
    for (int t = 0; t < 4; ++t) {
        const int brow = min(t * 16 + l16, KR - 1);
        bBase[t] = Wvb + (size_t)brow * DIM + quad * 8;
    }

    float4v acc[4];
    #pragma unroll
    for (int t = 0; t < 4; ++t) acc[t] = (float4v){0.f, 0.f, 0.f, 0.f};

    #pragma unroll 2
    for (int kc = 0; kc < DIM; kc += KC) {
        #pragma unroll
        for (int s = 0; s < 2; ++s) {           // two k-steps of 32 per chunk
            const float* ap = aBase + kc + s * 32;
            float4 v0 = *(const float4*)ap;
            float4 v1 = *(const float4*)(ap + 4);
            uint4 p;
            p.x = pack2_trunc(v0.x, v0.y);
            p.y = pack2_trunc(v0.z, v0.w);
            p.z = pack2_trunc(v1.x, v1.y);
            p.w = pack2_trunc(v1.z, v1.w);
            short8 af = __builtin_bit_cast(short8, p);
            #pragma unroll
            for (int t = 0; t < 4; ++t) {
                short8 bf = *(const short8*)(bBase[t] + kc + s * 32);
                acc[t] = __builtin_amdgcn_mfma_f32_16x16x32_bf16(af, bf, acc[t], 0, 0, 0);
            }
        }
    }

    // Epilogue: z_row = sum_col tanh(C[row,col] + Wgt[b(row),col]) * w_h[col]
    // lane holds C[row = rbase + quad*4 + r][col = t*16 + l16]
    float whv[4];
    #pragma unroll
    for (int t = 0; t < 4; ++t) {
        const int col = t * 16 + l16;
        whv[t] = (col < KR) ? w_h[col] : 0.f;   // masks padded cols
    }
    float zp[4] = {0.f, 0.f, 0.f, 0.f};
    #pragma unroll
    for (int r = 0; r < 4; ++r) {
        const int row = rbase + quad * 4 + r;
        const int brow = row / KR;              // batch of this output row
        const float* wgp = Wgt + (size_t)brow * KR;
        #pragma unroll
        for (int t = 0; t < 4; ++t) {
            const int col = t * 16 + l16;
            const float wg = wgp[min(col, KR - 1)];
            zp[r] += tanhf(acc[t][r] + wg) * whv[t];
        }
    }
    #pragma unroll
    for (int off = 1; off < 16; off <<= 1) {
        #pragma unroll
        for (int r = 0; r < 4; ++r)
            zp[r] += __shfl_xor(zp[r], off, 64);
    }
    if (l16 == 0) {
        #pragma unroll
        for (int r = 0; r < 4; ++r)
            zbuf[rbase + quad * 4 + r] = zp[r];
    }
}

// Kernel 3: streaming output. Two blocks per batch; softmax over the 50 logits
// recomputed in the wave-0 prologue (cheap), then out = beta*s + (1-beta)*alpha·V + h.
// Each thread produces exactly one float4 column.
__global__ __launch_bounds__(256) void out_kernel(
    const float* __restrict__ V, const float* __restrict__ h_t,
    const float* __restrict__ s_t, const float* __restrict__ zbuf,
    const float* __restrict__ Ts, float* __restrict__ out)
{
    const int bid = blockIdx.x;
    const int b   = bid >> 1;
    const int tid = threadIdx.x;
    const int d4  = ((bid & 1) << 8) + tid;    // 0..511

    __shared__ float alpha_l[KR];
    __shared__ float beta_sh;

    if (tid < 64) {
        const int lane = tid;
        float tv = (lane < KR) ? Ts[(size_t)b * KR + lane] : 0.f;
        float sent = tv;
        #pragma unroll
        for (int off = 1; off < 64; off <<= 1) sent += __shfl_xor(sent, off, 64);
        float x = (lane < KR) ? zbuf[(size_t)b * KR + lane]
                              : ((lane == KR) ? sent : -1e30f);
        float m = x;
        #pragma unroll
        for (int off = 1; off < 64; off <<= 1) m = fmaxf(m, __shfl_xor(m, off, 64));
        float e = (lane <= KR) ? expf(x - m) : 0.f;
        float s = e;
        #pragma unroll
        for (int off = 1; off < 64; off <<= 1) s += __shfl_xor(s, off, 64);
        const float a = e / s;
        if (lane < KR) alpha_l[lane] = a;
        if (lane == KR) beta_sh = a;
    }
    __syncthreads();

    const float bta = beta_sh;
    const float omb = 1.f - bta;
    const float4* vp = (const float4*)(V + (size_t)b * KR * DIM) + d4;
    float ax = 0.f, ay = 0.f, az = 0.f, aw = 0.f;
    #pragma unroll 7
    for (int l = 0; l < KR; ++l) {
        const float al = alpha_l[l];
        float4 v = vp[(size_t)l * (DIM / 4)];
        ax += al * v.x; ay += al * v.y; az += al * v.z; aw += al * v.w;
    }
    const float4 hv = ((const float4*)(h_t + (size_t)b * DIM))[d4];
    const float4 sv = ((const float4*)(s_t + (size_t)b * DIM))[d4];
    float4 o;
    o.x = bta * sv.x + omb * ax + hv.x;
    o.y = bta * sv.y + omb * ay + hv.y;
    o.z = bta * sv.z + omb * az + hv.z;
    o.w = bta * sv.w + omb * aw + hv.w;
    ((float4*)(out + (size_t)b * DIM))[d4] = o;
}

extern "C" void kernel_launch(void* const* d_in, const int* in_sizes, int n_in,
                              void* d_out, int out_size, void* d_ws, size_t ws_size,
                              hipStream_t stream) {
    const float* V     = (const float*)d_in[0];
    const float* h_t   = (const float*)d_in[1];
    const float* s_t   = (const float*)d_in[2];
    const float* W_v   = (const float*)d_in[3];
    const float* W_g   = (const float*)d_in[4];
    const float* W_s   = (const float*)d_in[5];
    const float* w_h   = (const float*)d_in[6];
    const float* w_h_s = (const float*)d_in[7];
    float* out = (float*)d_out;

    // ws layout: Wgt [B*49 f32] | Ts [B*49 f32] | zbuf [B*49 f32] | Wvb [49*2048 bf16]  (~1.4 MB)
    float* Wgt = (float*)d_ws;
    float* Ts  = Wgt + (size_t)BATCH * KR;
    float* zbuf = Ts + (size_t)BATCH * KR;
    unsigned short* Wvb = (unsigned short*)(zbuf + (size_t)BATCH * KR);

    hipLaunchKernelGGL(precompute_kernel, dim3((BATCH * KR + 255) / 256), dim3(256), 0, stream,
                       h_t, s_t, W_v, W_g, W_s, w_h_s, Wgt, Ts, Wvb);
    hipLaunchKernelGGL(z_gemm_kernel, dim3(NROW / 64), dim3(256), 0, stream,
                       V, Wvb, Wgt, w_h, zbuf);
    hipLaunchKernelGGL(out_kernel, dim3(BATCH * 2), dim3(256), 0, stream,
                       V, h_t, s_t, zbuf, Ts, out);
}